// Round 4
// baseline (398.296 us; speedup 1.0000x reference)
//
#include <hip/hip_runtime.h>

#define NB 16
#define NS 1024
#define NHID 64
#define NHEADS 4
#define NDH 16
#define LN_EPS 1e-5f
#define TQ 32
#define KT 64

// ---------------------------------------------------------------------------
// Kernel 1: QKV projection (unchanged).
// ---------------------------------------------------------------------------
__global__ __launch_bounds__(256) void qkv_kernel(
    const float* __restrict__ x,
    const float* __restrict__ Wq, const float* __restrict__ bq,
    const float* __restrict__ Wk, const float* __restrict__ bk,
    const float* __restrict__ Wv, const float* __restrict__ bv,
    float* __restrict__ qo, float* __restrict__ ko, float* __restrict__ vo)
{
    __shared__ float wqt[64][65], wkt[64][65], wvt[64][65];
    __shared__ float xs[32][64];
    int t = threadIdx.x;
    int row0 = blockIdx.x * 32;
    for (int i = t; i < 4096; i += 256) {
        int c = i >> 6, j = i & 63;
        wqt[j][c] = Wq[i];
        wkt[j][c] = Wk[i];
        wvt[j][c] = Wv[i];
    }
    for (int i = t; i < 2048; i += 256) {
        xs[i >> 6][i & 63] = x[(size_t)row0 * 64 + i];
    }
    __syncthreads();
    int c = t & 63, rq = t >> 6;
    int h = c >> 4, d = c & 15;
    float bqv = bq[c], bkv = bk[c], bvv = bv[c];
    for (int rr = 0; rr < 8; ++rr) {
        int r = rq * 8 + rr;
        float aq = bqv, ak = bkv, av = bvv;
        #pragma unroll
        for (int j = 0; j < 64; ++j) {
            float xv = xs[r][j];
            aq = fmaf(xv, wqt[j][c], aq);
            ak = fmaf(xv, wkt[j][c], ak);
            av = fmaf(xv, wvt[j][c], av);
        }
        int srow = row0 + r;
        int b_ = srow >> 10, s_ = srow & 1023;
        size_t o = (((size_t)(b_ * NHEADS + h)) * NS + s_) * NDH + d;
        qo[o] = aq; ko[o] = ak; vo[o] = av;
    }
}

// ---------------------------------------------------------------------------
// Kernel 2 (REWRITTEN): register-q-blocked attention.
// Block = (b, 32 q-rows). Wave = one head. Lane: qq = ln&7 (4 q-rows in regs),
// kp = ln>>3 (k-slot; 8 k's per 64-k tile). Q and O live in registers:
// one K/V LDS row read feeds 64 FMAs (was 1 FMA/float -> LDS-bound).
// Z / O reduced over kp-lanes via shfl_xor(8,16,32). amean head-sum via
// per-wave LDS buffers, flush overlapped with next tile staging.
// Block order reversed so heavy (high-q0) blocks dispatch first.
// ---------------------------------------------------------------------------
__global__ __launch_bounds__(256, 2) void attn3_kernel(
    const float* __restrict__ q, const float* __restrict__ k,
    const float* __restrict__ v, const int* __restrict__ lengths,
    float* __restrict__ amean,   // [B,S,S]
    float* __restrict__ out)     // [B,S,64]
{
    __shared__ float Klds[KT][68];
    __shared__ float Vlds[KT][68];
    __shared__ float alds[NHEADS][TQ][65];

    const int t  = threadIdx.x;
    const int h  = t >> 6;                 // wave = head
    const int ln = t & 63;
    const int qq = ln & 7;                 // q-quad
    const int kp = ln >> 3;                // k-slot
    const int bx = (int)gridDim.x - 1 - (int)blockIdx.x;   // heavy first
    const int q0 = bx * TQ;
    const int b  = blockIdx.y;
    const int len = lengths[b];
    const int qrow0 = q0 + qq * 4;

    // Q rows qq*4+r of head h -> registers
    float4 qv[4][4];
    #pragma unroll
    for (int r = 0; r < 4; ++r) {
        const float4* qp = (const float4*)
            &q[(((size_t)(b * NHEADS + h)) * NS + qrow0 + r) * NDH];
        qv[r][0] = qp[0]; qv[r][1] = qp[1]; qv[r][2] = qp[2]; qv[r][3] = qp[3];
    }

    const int nk = (len <= q0) ? 0 : min(q0 + TQ, len);
    const int ntiles = (nk + KT - 1) >> 6;

    // ---------------- pass 1: Z = sum exp(score) ----------------
    float Z[4] = {0.f, 0.f, 0.f, 0.f};
    for (int tile = 0; tile < ntiles; ++tile) {
        const int k0 = tile << 6;
        #pragma unroll
        for (int i = 0; i < 4; ++i) {
            int idx = t + 256 * i, kk = idx >> 4, j4 = idx & 15;
            *(float4*)&Klds[kk][j4 * 4] = *(const float4*)
                &k[(((size_t)(b * NHEADS + (j4 >> 2))) * NS + k0 + kk) * NDH + (j4 & 3) * 4];
        }
        __syncthreads();
        #pragma unroll
        for (int kki = 0; kki < 8; ++kki) {
            const int kk = kki * 8 + kp, kg = k0 + kk;
            const float4* rk = (const float4*)&Klds[kk][h * 16];
            const float4 ka = rk[0], kb = rk[1], kc = rk[2], kd = rk[3];
            #pragma unroll
            for (int r = 0; r < 4; ++r) {
                const int qrow = qrow0 + r;
                float s = ka.x * qv[r][0].x + ka.y * qv[r][0].y
                        + ka.z * qv[r][0].z + ka.w * qv[r][0].w
                        + kb.x * qv[r][1].x + kb.y * qv[r][1].y
                        + kb.z * qv[r][1].z + kb.w * qv[r][1].w
                        + kc.x * qv[r][2].x + kc.y * qv[r][2].y
                        + kc.z * qv[r][2].z + kc.w * qv[r][2].w
                        + kd.x * qv[r][3].x + kd.y * qv[r][3].y
                        + kd.z * qv[r][3].z + kd.w * qv[r][3].w;
                const bool valid = (qrow < len) && (kg <= qrow);
                Z[r] += valid ? __expf(s * 0.125f) : 0.f;
            }
        }
        __syncthreads();
    }
    #pragma unroll
    for (int m = 8; m <= 32; m <<= 1) {
        #pragma unroll
        for (int r = 0; r < 4; ++r) Z[r] += __shfl_xor(Z[r], m, 64);
    }
    float iz[4];
    #pragma unroll
    for (int r = 0; r < 4; ++r) iz[r] = (Z[r] > 0.f) ? 1.f / Z[r] : 0.f;

    // ---------------- pass 2: probs, amean, PV ----------------
    float4 o4[4][4];
    #pragma unroll
    for (int r = 0; r < 4; ++r)
        #pragma unroll
        for (int i = 0; i < 4; ++i) o4[r][i] = make_float4(0.f, 0.f, 0.f, 0.f);

    // prologue stage of tile 0
    if (ntiles > 0) {
        #pragma unroll
        for (int i = 0; i < 4; ++i) {
            int idx = t + 256 * i, kk = idx >> 4, j4 = idx & 15;
            size_t goff = (((size_t)(b * NHEADS + (j4 >> 2))) * NS + kk) * NDH + (j4 & 3) * 4;
            *(float4*)&Klds[kk][j4 * 4] = *(const float4*)&k[goff];
            *(float4*)&Vlds[kk][j4 * 4] = *(const float4*)&v[goff];
        }
        __syncthreads();
    }
    for (int tile = 0; tile < ntiles; ++tile) {
        const int k0 = tile << 6;
        #pragma unroll
        for (int kki = 0; kki < 8; ++kki) {
            const int kk = kki * 8 + kp, kg = k0 + kk;
            const float4* rk = (const float4*)&Klds[kk][h * 16];
            const float4 ka = rk[0], kb = rk[1], kc = rk[2], kd = rk[3];
            const float4* rv = (const float4*)&Vlds[kk][h * 16];
            const float4 va = rv[0], vb = rv[1], vc = rv[2], vd = rv[3];
            #pragma unroll
            for (int r = 0; r < 4; ++r) {
                const int qrow = qrow0 + r;
                float s = ka.x * qv[r][0].x + ka.y * qv[r][0].y
                        + ka.z * qv[r][0].z + ka.w * qv[r][0].w
                        + kb.x * qv[r][1].x + kb.y * qv[r][1].y
                        + kb.z * qv[r][1].z + kb.w * qv[r][1].w
                        + kc.x * qv[r][2].x + kc.y * qv[r][2].y
                        + kc.z * qv[r][2].z + kc.w * qv[r][2].w
                        + kd.x * qv[r][3].x + kd.y * qv[r][3].y
                        + kd.z * qv[r][3].z + kd.w * qv[r][3].w;
                const bool valid = (qrow < len) && (kg <= qrow);
                const float p = (valid ? __expf(s * 0.125f) : 0.f) * iz[r];
                alds[h][qq * 4 + r][kk] = 0.25f * p;
                o4[r][0].x = fmaf(p, va.x, o4[r][0].x);
                o4[r][0].y = fmaf(p, va.y, o4[r][0].y);
                o4[r][0].z = fmaf(p, va.z, o4[r][0].z);
                o4[r][0].w = fmaf(p, va.w, o4[r][0].w);
                o4[r][1].x = fmaf(p, vb.x, o4[r][1].x);
                o4[r][1].y = fmaf(p, vb.y, o4[r][1].y);
                o4[r][1].z = fmaf(p, vb.z, o4[r][1].z);
                o4[r][1].w = fmaf(p, vb.w, o4[r][1].w);
                o4[r][2].x = fmaf(p, vc.x, o4[r][2].x);
                o4[r][2].y = fmaf(p, vc.y, o4[r][2].y);
                o4[r][2].z = fmaf(p, vc.z, o4[r][2].z);
                o4[r][2].w = fmaf(p, vc.w, o4[r][2].w);
                o4[r][3].x = fmaf(p, vd.x, o4[r][3].x);
                o4[r][3].y = fmaf(p, vd.y, o4[r][3].y);
                o4[r][3].z = fmaf(p, vd.z, o4[r][3].z);
                o4[r][3].w = fmaf(p, vd.w, o4[r][3].w);
            }
        }
        __syncthreads();
        // flush this tile's amean (head-sum) + stage next tile, overlapped
        #pragma unroll
        for (int i = 0; i < 2; ++i) {
            int idx = t + 256 * i, r = idx >> 4, c4 = idx & 15;
            float4 w4;
            w4.x = alds[0][r][c4 * 4 + 0] + alds[1][r][c4 * 4 + 0]
                 + alds[2][r][c4 * 4 + 0] + alds[3][r][c4 * 4 + 0];
            w4.y = alds[0][r][c4 * 4 + 1] + alds[1][r][c4 * 4 + 1]
                 + alds[2][r][c4 * 4 + 1] + alds[3][r][c4 * 4 + 1];
            w4.z = alds[0][r][c4 * 4 + 2] + alds[1][r][c4 * 4 + 2]
                 + alds[2][r][c4 * 4 + 2] + alds[3][r][c4 * 4 + 2];
            w4.w = alds[0][r][c4 * 4 + 3] + alds[1][r][c4 * 4 + 3]
                 + alds[2][r][c4 * 4 + 3] + alds[3][r][c4 * 4 + 3];
            *(float4*)&amean[((size_t)(b * NS + q0 + r)) * NS + k0 + c4 * 4] = w4;
        }
        if (tile + 1 < ntiles) {
            const int kn = (tile + 1) << 6;
            #pragma unroll
            for (int i = 0; i < 4; ++i) {
                int idx = t + 256 * i, kk = idx >> 4, j4 = idx & 15;
                size_t goff = (((size_t)(b * NHEADS + (j4 >> 2))) * NS + kn + kk) * NDH + (j4 & 3) * 4;
                *(float4*)&Klds[kk][j4 * 4] = *(const float4*)&k[goff];
                *(float4*)&Vlds[kk][j4 * 4] = *(const float4*)&v[goff];
            }
        }
        __syncthreads();
    }

    // O reduce across kp-lanes, then store
    #pragma unroll
    for (int m = 8; m <= 32; m <<= 1) {
        #pragma unroll
        for (int r = 0; r < 4; ++r) {
            #pragma unroll
            for (int i = 0; i < 4; ++i) {
                o4[r][i].x += __shfl_xor(o4[r][i].x, m, 64);
                o4[r][i].y += __shfl_xor(o4[r][i].y, m, 64);
                o4[r][i].z += __shfl_xor(o4[r][i].z, m, 64);
                o4[r][i].w += __shfl_xor(o4[r][i].w, m, 64);
            }
        }
    }
    if (kp == 0) {
        #pragma unroll
        for (int r = 0; r < 4; ++r)
            #pragma unroll
            for (int i = 0; i < 4; ++i)
                *(float4*)&out[((size_t)(b * NS + qrow0 + r)) * NHID + h * 16 + i * 4] = o4[r][i];
    }

    // zero-fill amean columns beyond processed tiles
    const int kz = ntiles << 6;
    const int nz4 = (NS - kz) >> 2;
    const float4 z4 = make_float4(0.f, 0.f, 0.f, 0.f);
    for (int r = 0; r < TQ; ++r) {
        for (int c4 = t; c4 < nz4; c4 += 256) {
            *(float4*)&amean[((size_t)(b * NS + q0 + r)) * NS + kz + c4 * 4] = z4;
        }
    }
}

// ---------------------------------------------------------------------------
// Kernel 3: residual + LN1 + FFN(GELU exact) + residual + LN2 (unchanged).
// ---------------------------------------------------------------------------
__device__ __forceinline__ float wsum(float v) {
    #pragma unroll
    for (int o = 32; o > 0; o >>= 1) v += __shfl_xor(v, o, 64);
    return v;
}

__global__ __launch_bounds__(256) void ffn_kernel(
    const float* __restrict__ x, const float* __restrict__ aout,
    const float* __restrict__ W1, const float* __restrict__ b1,
    const float* __restrict__ W2, const float* __restrict__ b2,
    const float* __restrict__ g1, const float* __restrict__ be1,
    const float* __restrict__ g2, const float* __restrict__ be2,
    float* __restrict__ y)
{
    __shared__ float w1t[64][65], w2t[64][65];
    __shared__ float n1sh[4][64], h1sh[4][64];
    int t = threadIdx.x;
    for (int i = t; i < 4096; i += 256) {
        int c = i >> 6, j = i & 63;
        w1t[j][c] = W1[i];
        w2t[j][c] = W2[i];
    }
    __syncthreads();
    int wv = t >> 6, d = t & 63;
    size_t row = (size_t)blockIdx.x * 4 + wv;

    float o1 = x[row * 64 + d] + aout[row * 64 + d];
    float mu = wsum(o1) * (1.f / 64.f);
    float diff = o1 - mu;
    float var = wsum(diff * diff) * (1.f / 64.f);
    float n1 = diff * rsqrtf(var + LN_EPS) * g1[d] + be1[d];
    n1sh[wv][d] = n1;
    __syncthreads();
    float acc = b1[d];
    #pragma unroll
    for (int j = 0; j < 64; ++j) acc = fmaf(n1sh[wv][j], w1t[j][d], acc);
    float ge = 0.5f * acc * (1.f + erff(acc * 0.70710678118654752f));
    h1sh[wv][d] = ge;
    __syncthreads();
    float acc2 = b2[d];
    #pragma unroll
    for (int j = 0; j < 64; ++j) acc2 = fmaf(h1sh[wv][j], w2t[j][d], acc2);
    float z = n1 + acc2;
    float mu2 = wsum(z) * (1.f / 64.f);
    float d2 = z - mu2;
    float var2 = wsum(d2 * d2) * (1.f / 64.f);
    float yv = d2 * rsqrtf(var2 + LN_EPS) * g2[d] + be2[d];
    y[row * 64 + d] = yv;
}

// ---------------------------------------------------------------------------
extern "C" void kernel_launch(void* const* d_in, const int* in_sizes, int n_in,
                              void* d_out, int out_size, void* d_ws, size_t ws_size,
                              hipStream_t stream) {
    const float* x   = (const float*)d_in[0];
    const int* lengths = (const int*)d_in[1];
    const float* Wq  = (const float*)d_in[3];
    const float* bq  = (const float*)d_in[4];
    const float* Wk  = (const float*)d_in[5];
    const float* bk  = (const float*)d_in[6];
    const float* Wv  = (const float*)d_in[7];
    const float* bv  = (const float*)d_in[8];
    const float* W1  = (const float*)d_in[9];
    const float* b1  = (const float*)d_in[10];
    const float* W2  = (const float*)d_in[11];
    const float* b2  = (const float*)d_in[12];
    const float* g1  = (const float*)d_in[13];
    const float* be1 = (const float*)d_in[14];
    const float* g2  = (const float*)d_in[15];
    const float* be2 = (const float*)d_in[16];

    float* y     = (float*)d_out;                       // [B,S,64]
    float* amean = y + (size_t)NB * NS * NHID;          // [B,S,S]

    float* qw    = (float*)d_ws;                        // [B,NH,S,DH]
    float* kw    = qw + (size_t)NB * NHEADS * NS * NDH;
    float* vw    = kw + (size_t)NB * NHEADS * NS * NDH;
    float* aoutw = vw + (size_t)NB * NHEADS * NS * NDH; // [B,S,64]

    hipLaunchKernelGGL(qkv_kernel, dim3(NB * NS / 32), dim3(256), 0, stream,
                       x, Wq, bq, Wk, bk, Wv, bv, qw, kw, vw);
    hipLaunchKernelGGL(attn3_kernel, dim3(NS / TQ, NB), dim3(256), 0, stream,
                       qw, kw, vw, lengths, amean, aoutw);
    hipLaunchKernelGGL(ffn_kernel, dim3(NB * NS / 4), dim3(256), 0, stream,
                       x, aoutw, W1, b1, W2, b2, g1, be1, g2, be2, y);
}